// Round 3
// baseline (251.024 us; speedup 1.0000x reference)
//
#include <hip/hip_runtime.h>
#include <hip/hip_bf16.h>

#define D_MODEL 4096
#define NTOK    8192   // B*S = 4*2048
#define SEQ     2048

typedef short bf16x8 __attribute__((ext_vector_type(8)));  // 8 bf16 in 4 VGPRs
typedef float f32x4  __attribute__((ext_vector_type(4)));

__device__ inline short f2bf(float x) {
  __hip_bfloat16 h = __float2bfloat16(x);
  return *reinterpret_cast<short*>(&h);
}
__device__ inline float bf2f(const void* p, size_t i) {
  return __bfloat162float(((const __hip_bfloat16*)p)[i]);
}

// ---------------------------------------------------------------------------
// Kernel 0: dtype sniffing. One wave per tensor. flag=1 -> read as bf16[],
// flag=0 -> read as float[]. (Evidence so far: hidden=bf16, weights=f32.)
// ---------------------------------------------------------------------------
__global__ __launch_bounds__(320) void sniff_k(const void* hid, const void* wf,
                                               const void* w1, const void* w2,
                                               const void* b1, const void* b2,
                                               const void* lam,
                                               int* flags, float* scal) {
  int wv = threadIdx.x >> 6, lane = threadIdx.x & 63;
  const unsigned short* p = nullptr;
  int n = 0;
  switch (wv) {
    case 0: p = (const unsigned short*)hid; n = NTOK * D_MODEL; break;
    case 1: p = (const unsigned short*)wf;  n = 16 * D_MODEL;   break;
    case 2: p = (const unsigned short*)w1;  n = 64 * 4112;      break;
    case 3: p = (const unsigned short*)w2;  n = 64;             break;
    case 4: p = (const unsigned short*)b1;  n = 64;             break;
  }
  int S = n / 2 < 64 ? n / 2 : 64;
  bool act = lane < S;
  unsigned short ve = 0, vo = 0;
  if (act) { ve = p[2 * lane]; vo = p[2 * lane + 1]; }
  int ee = (ve >> 7) & 0xFF, eo = (vo >> 7) & 0xFF;
  bool ve_band   = (ve == 0) || (ve == 0x8000) || (ee >= 96 && ee <= 141);
  bool vo_bandnz = (vo != 0) && (vo != 0x8000) && (eo >= 96 && eo <= 141);
  int zp = __popcll(__ballot(act && ve == 0 && vo == 0));
  int ob = __popcll(__ballot(act && ve == 0 && vo_bandnz));
  int eb = __popcll(__ballot(act && ve_band));
  if (lane == 0) {
    int f;
    if (zp == S) f = 1;                 // all zeros: bf16-read is value-correct
    else if (4 * ob >= 3 * S) f = 0;    // f32 storage of bf16-rounded values
    else if (4 * eb >= 3 * S) f = 1;    // true bf16
    else f = 0;                         // raw f32
    flags[wv] = f;
  }
  if (threadIdx.x == 0) {
    unsigned short l0 = *(const unsigned short*)lam;
    int le = (l0 >> 7) & 0xFF;
    if (l0 != 0 && l0 != 0x8000 && le >= 96 && le <= 141)
      scal[0] = __bfloat162float(*(const __hip_bfloat16*)lam);
    else
      scal[0] = *(const float*)lam;
    unsigned short c0 = *(const unsigned short*)b2;
    int ce = (c0 >> 7) & 0xFF;
    if (c0 == 0) scal[1] = 0.0f;
    else if (c0 != 0x8000 && ce >= 96 && ce <= 141)
      scal[1] = __bfloat162float(*(const __hip_bfloat16*)b2);
    else
      scal[1] = *(const float*)b2;
  }
}

// ---------------------------------------------------------------------------
// Kernel 1: fold W_fiber into W1 -> W1_eff[64][4096] bf16 (internal format).
// W1_eff[n][k] = W1[n][k] + sum_f W1[n][4096+f] * W_fiber[f][k]
// ---------------------------------------------------------------------------
__global__ __launch_bounds__(256) void fold_w1(const void* __restrict__ W1v,
                                               const void* __restrict__ Wfv,
                                               const int* __restrict__ flags,
                                               __hip_bfloat16* __restrict__ W1eff) {
  int n = blockIdx.x;  // 0..63
  int fw1 = flags[2], fwf = flags[1];
  __shared__ float w1b[16];
  if (threadIdx.x < 16) {
    size_t idx = (size_t)n * 4112 + 4096 + threadIdx.x;
    w1b[threadIdx.x] = fw1 ? bf2f(W1v, idx) : ((const float*)W1v)[idx];
  }
  __syncthreads();
  for (int k = threadIdx.x; k < D_MODEL; k += 256) {
    size_t idx = (size_t)n * 4112 + k;
    float v = fw1 ? bf2f(W1v, idx) : ((const float*)W1v)[idx];
#pragma unroll
    for (int f = 0; f < 16; ++f) {
      size_t wi = (size_t)f * D_MODEL + k;
      float wfv = fwf ? bf2f(Wfv, wi) : ((const float*)Wfv)[wi];
      v += w1b[f] * wfv;
    }
    W1eff[(size_t)n * D_MODEL + k] = __float2bfloat16(v);
  }
}

// ---------------------------------------------------------------------------
// Kernel 2: fused skinny GEMM + epilogue -> delta[8192].
// Block = 256 thr (4 waves); wave w owns K-chunk w (1024). 16x16x32 bf16 MFMA,
// A-frag A[m=lane&15][k=8*(lane>>4)+j]; B-frag from W1eff[n][k] (B^T form);
// C: col(n)=lane&15, row(m)=(lane>>4)*4+reg (m89/m91-verified).
// LDS reduce over 4 chunks, + b1, exact GELU, dot W2, + b2, softplus.
// ---------------------------------------------------------------------------
__global__ __launch_bounds__(256) void gemm_delta(const void* __restrict__ hid,
                                                  const short* __restrict__ B_,
                                                  const void* __restrict__ b1,
                                                  const void* __restrict__ w2,
                                                  const int* __restrict__ flags,
                                                  const float* __restrict__ scal,
                                                  float* __restrict__ delta) {
  int tile = blockIdx.x;            // 0..511
  int w    = threadIdx.x >> 6;      // K-chunk 0..3
  int lane = threadIdx.x & 63;
  int m = lane & 15, kg = lane >> 4;
  size_t abase = (size_t)(tile * 16 + m) * D_MODEL + w * 1024 + kg * 8;
  const short* Bp = B_ + (size_t)m * D_MODEL + w * 1024 + kg * 8;
  f32x4 acc0 = {0.f, 0.f, 0.f, 0.f};
  f32x4 acc1 = acc0, acc2 = acc0, acc3 = acc0;
  if (flags[0]) {  // hidden is bf16
    const short* Ap = (const short*)hid + abase;
#pragma unroll 4
    for (int ks = 0; ks < 1024; ks += 32) {
      bf16x8 a   = *(const bf16x8*)(Ap + ks);
      bf16x8 b0  = *(const bf16x8*)(Bp + ks);
      bf16x8 b1f = *(const bf16x8*)(Bp + 16 * D_MODEL + ks);
      bf16x8 b2f = *(const bf16x8*)(Bp + 32 * D_MODEL + ks);
      bf16x8 b3f = *(const bf16x8*)(Bp + 48 * D_MODEL + ks);
      acc0 = __builtin_amdgcn_mfma_f32_16x16x32_bf16(a, b0, acc0, 0, 0, 0);
      acc1 = __builtin_amdgcn_mfma_f32_16x16x32_bf16(a, b1f, acc1, 0, 0, 0);
      acc2 = __builtin_amdgcn_mfma_f32_16x16x32_bf16(a, b2f, acc2, 0, 0, 0);
      acc3 = __builtin_amdgcn_mfma_f32_16x16x32_bf16(a, b3f, acc3, 0, 0, 0);
    }
  } else {  // hidden is f32: load f32, convert to bf16 fragments
    const float* Ap = (const float*)hid + abase;
#pragma unroll 2
    for (int ks = 0; ks < 1024; ks += 32) {
      float4 lo = *(const float4*)(Ap + ks);
      float4 hi = *(const float4*)(Ap + ks + 4);
      bf16x8 a;
      a[0] = f2bf(lo.x); a[1] = f2bf(lo.y); a[2] = f2bf(lo.z); a[3] = f2bf(lo.w);
      a[4] = f2bf(hi.x); a[5] = f2bf(hi.y); a[6] = f2bf(hi.z); a[7] = f2bf(hi.w);
      bf16x8 b0  = *(const bf16x8*)(Bp + ks);
      bf16x8 b1f = *(const bf16x8*)(Bp + 16 * D_MODEL + ks);
      bf16x8 b2f = *(const bf16x8*)(Bp + 32 * D_MODEL + ks);
      bf16x8 b3f = *(const bf16x8*)(Bp + 48 * D_MODEL + ks);
      acc0 = __builtin_amdgcn_mfma_f32_16x16x32_bf16(a, b0, acc0, 0, 0, 0);
      acc1 = __builtin_amdgcn_mfma_f32_16x16x32_bf16(a, b1f, acc1, 0, 0, 0);
      acc2 = __builtin_amdgcn_mfma_f32_16x16x32_bf16(a, b2f, acc2, 0, 0, 0);
      acc3 = __builtin_amdgcn_mfma_f32_16x16x32_bf16(a, b3f, acc3, 0, 0, 0);
    }
  }
  __shared__ float red[4][16][64];  // 16 KB
#pragma unroll
  for (int r = 0; r < 4; ++r) {
    int row = kg * 4 + r;
    red[w][row][ 0 + m] = acc0[r];
    red[w][row][16 + m] = acc1[r];
    red[w][row][32 + m] = acc2[r];
    red[w][row][48 + m] = acc3[r];
  }
  __syncthreads();
  // epilogue: thread t -> row = t>>4, cid = t&15 handles cols cid+16j
  int row = threadIdx.x >> 4, cid = threadIdx.x & 15;
  int fb1 = flags[4], fw2 = flags[3];
  float y = 0.f;
#pragma unroll
  for (int j = 0; j < 4; ++j) {
    int c = cid + 16 * j;
    float s = red[0][row][c] + red[1][row][c] + red[2][row][c] + red[3][row][c];
    s += fb1 ? bf2f(b1, c) : ((const float*)b1)[c];
    float g = 0.5f * s * (1.0f + erff(s * 0.70710678118654752f));  // exact GELU
    y += g * (fw2 ? bf2f(w2, c) : ((const float*)w2)[c]);
  }
#pragma unroll
  for (int off = 1; off <= 8; off <<= 1) y += __shfl_xor(y, off, 64);
  if (cid == 0) {
    float x = y + scal[1];  // + b2
    float d = (x > 20.0f) ? x : log1pf(expf(x));  // softplus
    delta[tile * 16 + row] = d;
  }
}

// ---------------------------------------------------------------------------
// Kernel 3: causal EMA, gate, field, mean. OUTPUT IS FLOAT32 (mixed-dtype
// tuple (bf16,bf16,f32) is concatenated by the harness -> numpy-promoted f32).
// 1 block, 4 waves (one per batch). Lane-local 32-step serial + Kogge-Stone
// scan of affine transforms (A=0.9^32, B=local EMA) across 64 lanes.
// ---------------------------------------------------------------------------
__global__ __launch_bounds__(256) void ema_out(const float* __restrict__ delta,
                                               const float* __restrict__ scal,
                                               float* __restrict__ out) {
  int b    = threadIdx.x >> 6;   // batch 0..3
  int lane = threadIdx.x & 63;
  const float alpha = 0.9f;
  float d[32];
  const float* dp = delta + b * SEQ + lane * 32;
  float beta = 0.f, lsum = 0.f;
#pragma unroll
  for (int i = 0; i < 32; ++i) {
    d[i] = dp[i];
    lsum += d[i];
    beta = alpha * beta + 0.1f * d[i];
  }
  float accA = 0.03433683820292512f;  // 0.9^32
  float accB = beta;
  for (int off = 1; off < 64; off <<= 1) {
    float uA = __shfl_up(accA, off, 64);
    float uB = __shfl_up(accB, off, 64);
    if (lane >= off) {
      accB = accB + accA * uB;  // cur o prev
      accA = accA * uA;
    }
  }
  float prev = __shfl_up(accB, 1, 64);
  float h = (lane == 0) ? 0.f : prev;  // carry-in state for this chunk
  float lam = scal[0];
#pragma unroll
  for (int i = 0; i < 32; ++i) {
    h = alpha * h + 0.1f * d[i];
    float gate = 1.0f / (1.0f + expf(lam * h));  // sigmoid(-lam*h)
    out[b * SEQ + lane * 32 + i]        = gate;
    out[NTOK + b * SEQ + lane * 32 + i] = h;
  }
#pragma unroll
  for (int off = 32; off >= 1; off >>= 1) lsum += __shfl_xor(lsum, off, 64);
  __shared__ float bs[4];
  if (lane == 0) bs[b] = lsum;
  __syncthreads();
  if (threadIdx.x == 0)
    out[2 * NTOK] = (bs[0] + bs[1] + bs[2] + bs[3]) * (1.0f / 8192.0f);
}

// ---------------------------------------------------------------------------
extern "C" void kernel_launch(void* const* d_in, const int* in_sizes, int n_in,
                              void* d_out, int out_size, void* d_ws, size_t ws_size,
                              hipStream_t stream) {
  const void* hidden = d_in[0];  // [4,2048,4096]
  const void* Wf     = d_in[1];  // [16,4096]
  const void* W1     = d_in[2];  // [64,4112]
  const void* b1     = d_in[3];  // [64]
  const void* W2     = d_in[4];  // [1,64]
  const void* b2     = d_in[5];  // [1]
  const void* lam    = d_in[6];  // [1]
  float* out = (float*)d_out;    // 16385 f32 (gate 8192 | field 8192 | mean 1)

  // workspace: [0,32) int flags, [32,40) float scal, [64, 64+512K) W1eff bf16,
  // then delta f32 (32 KB). Total ~557 KB.
  char* ws = (char*)d_ws;
  int*   flags = (int*)ws;
  float* scal  = (float*)(ws + 32);
  __hip_bfloat16* W1eff = (__hip_bfloat16*)(ws + 64);
  float* delta = (float*)(ws + 64 + (size_t)64 * D_MODEL * 2);

  sniff_k<<<1, 320, 0, stream>>>(hidden, Wf, W1, W2, b1, b2, lam, flags, scal);
  fold_w1<<<64, 256, 0, stream>>>(W1, Wf, flags, W1eff);
  gemm_delta<<<512, 256, 0, stream>>>(hidden, (const short*)W1eff, b1, W2, flags, scal, delta);
  ema_out<<<1, 256, 0, stream>>>(delta, scal, out);
}

// Round 4
// 247.279 us; speedup vs baseline: 1.0151x; 1.0151x over previous
//
#include <hip/hip_runtime.h>
#include <hip/hip_bf16.h>

#define D_MODEL 4096
#define NTOK    8192   // B*S = 4*2048
#define SEQ     2048

typedef short bf16x8 __attribute__((ext_vector_type(8)));  // 8 bf16 in 4 VGPRs
typedef float f32x4  __attribute__((ext_vector_type(4)));

__device__ inline short f2bf(float x) {
  __hip_bfloat16 h = __float2bfloat16(x);
  return *reinterpret_cast<short*>(&h);
}
__device__ inline float bf2f(const void* p, size_t i) {
  return __bfloat162float(((const __hip_bfloat16*)p)[i]);
}

// ---------------------------------------------------------------------------
// Kernel 0: dtype sniffing. One wave per tensor. flag=1 -> read as bf16[],
// flag=0 -> read as float[]. (Confirmed R3: hidden=bf16, weights=f32.)
// ---------------------------------------------------------------------------
__global__ __launch_bounds__(320) void sniff_k(const void* hid, const void* wf,
                                               const void* w1, const void* w2,
                                               const void* b1, const void* b2,
                                               const void* lam,
                                               int* flags, float* scal) {
  int wv = threadIdx.x >> 6, lane = threadIdx.x & 63;
  const unsigned short* p = nullptr;
  int n = 0;
  switch (wv) {
    case 0: p = (const unsigned short*)hid; n = NTOK * D_MODEL; break;
    case 1: p = (const unsigned short*)wf;  n = 16 * D_MODEL;   break;
    case 2: p = (const unsigned short*)w1;  n = 64 * 4112;      break;
    case 3: p = (const unsigned short*)w2;  n = 64;             break;
    case 4: p = (const unsigned short*)b1;  n = 64;             break;
  }
  int S = n / 2 < 64 ? n / 2 : 64;
  bool act = lane < S;
  unsigned short ve = 0, vo = 0;
  if (act) { ve = p[2 * lane]; vo = p[2 * lane + 1]; }
  int ee = (ve >> 7) & 0xFF, eo = (vo >> 7) & 0xFF;
  bool ve_band   = (ve == 0) || (ve == 0x8000) || (ee >= 96 && ee <= 141);
  bool vo_bandnz = (vo != 0) && (vo != 0x8000) && (eo >= 96 && eo <= 141);
  int zp = __popcll(__ballot(act && ve == 0 && vo == 0));
  int ob = __popcll(__ballot(act && ve == 0 && vo_bandnz));
  int eb = __popcll(__ballot(act && ve_band));
  if (lane == 0) {
    int f;
    if (zp == S) f = 1;
    else if (4 * ob >= 3 * S) f = 0;    // f32 storage of bf16-rounded values
    else if (4 * eb >= 3 * S) f = 1;    // true bf16
    else f = 0;                         // raw f32
    flags[wv] = f;
  }
  if (threadIdx.x == 0) {
    unsigned short l0 = *(const unsigned short*)lam;
    int le = (l0 >> 7) & 0xFF;
    if (l0 != 0 && l0 != 0x8000 && le >= 96 && le <= 141)
      scal[0] = __bfloat162float(*(const __hip_bfloat16*)lam);
    else
      scal[0] = *(const float*)lam;
    unsigned short c0 = *(const unsigned short*)b2;
    int ce = (c0 >> 7) & 0xFF;
    if (c0 == 0) scal[1] = 0.0f;
    else if (c0 != 0x8000 && ce >= 96 && ce <= 141)
      scal[1] = __bfloat162float(*(const __hip_bfloat16*)b2);
    else
      scal[1] = *(const float*)b2;
  }
}

// ---------------------------------------------------------------------------
// Kernel 1: fold W_fiber into W1 -> W1_eff[64][4096] bf16 (internal format).
// ---------------------------------------------------------------------------
__global__ __launch_bounds__(256) void fold_w1(const void* __restrict__ W1v,
                                               const void* __restrict__ Wfv,
                                               const int* __restrict__ flags,
                                               __hip_bfloat16* __restrict__ W1eff) {
  int n = blockIdx.x;  // 0..63
  int fw1 = flags[2], fwf = flags[1];
  __shared__ float w1b[16];
  if (threadIdx.x < 16) {
    size_t idx = (size_t)n * 4112 + 4096 + threadIdx.x;
    w1b[threadIdx.x] = fw1 ? bf2f(W1v, idx) : ((const float*)W1v)[idx];
  }
  __syncthreads();
  for (int k = threadIdx.x; k < D_MODEL; k += 256) {
    size_t idx = (size_t)n * 4112 + k;
    float v = fw1 ? bf2f(W1v, idx) : ((const float*)W1v)[idx];
#pragma unroll
    for (int f = 0; f < 16; ++f) {
      size_t wi = (size_t)f * D_MODEL + k;
      float wfv = fwf ? bf2f(Wfv, wi) : ((const float*)Wfv)[wi];
      v += w1b[f] * wfv;
    }
    W1eff[(size_t)n * D_MODEL + k] = __float2bfloat16(v);
  }
}

// ---------------------------------------------------------------------------
// Kernel 2: fused skinny GEMM + epilogue -> delta[8192].
// Block = 512 thr (8 waves, split-K 8: wave w owns K in [w*512, w*512+512)).
// Grid = 512 tiles of 16 rows -> 16 waves/CU (VGPR<=128 via launch_bounds).
// 8-deep rolling register prefetch of A fragments restores MLP (R3 showed
// VGPR=40 -> ~1 load in flight -> 885 GB/s latency-bound).
// MFMA 16x16x32 bf16; A-frag A[m=lane&15][k=8*(lane>>4)+j]; B=W1eff[n][k];
// C: col(n)=lane&15, row(m)=(lane>>4)*4+reg. LDS reduce over 8 chunks,
// + b1, exact GELU, dot W2, + b2, softplus.
// ---------------------------------------------------------------------------
__global__ __launch_bounds__(512, 4) void gemm_delta(const void* __restrict__ hid,
                                                     const short* __restrict__ B_,
                                                     const void* __restrict__ b1,
                                                     const void* __restrict__ w2,
                                                     const int* __restrict__ flags,
                                                     const float* __restrict__ scal,
                                                     float* __restrict__ delta) {
  int tile = blockIdx.x;            // 0..511
  int w    = threadIdx.x >> 6;      // K-chunk 0..7 (512 each)
  int lane = threadIdx.x & 63;
  int m = lane & 15, kg = lane >> 4;
  size_t abase = (size_t)(tile * 16 + m) * D_MODEL + w * 512 + kg * 8;
  const short* Bp = B_ + (size_t)m * D_MODEL + w * 512 + kg * 8;
  f32x4 acc0 = {0.f, 0.f, 0.f, 0.f};
  f32x4 acc1 = acc0, acc2 = acc0, acc3 = acc0;
  if (flags[0]) {  // hidden is bf16 (confirmed path)
    const short* Ap = (const short*)hid + abase;
    bf16x8 areg[8];
#pragma unroll
    for (int s = 0; s < 8; ++s) areg[s] = *(const bf16x8*)(Ap + s * 32);
#pragma unroll
    for (int s = 0; s < 16; ++s) {
      bf16x8 a = areg[s & 7];
      if (s + 8 < 16) areg[s & 7] = *(const bf16x8*)(Ap + (s + 8) * 32);
      bf16x8 b0  = *(const bf16x8*)(Bp + s * 32);
      bf16x8 b1f = *(const bf16x8*)(Bp + 16 * D_MODEL + s * 32);
      bf16x8 b2f = *(const bf16x8*)(Bp + 32 * D_MODEL + s * 32);
      bf16x8 b3f = *(const bf16x8*)(Bp + 48 * D_MODEL + s * 32);
      acc0 = __builtin_amdgcn_mfma_f32_16x16x32_bf16(a, b0, acc0, 0, 0, 0);
      acc1 = __builtin_amdgcn_mfma_f32_16x16x32_bf16(a, b1f, acc1, 0, 0, 0);
      acc2 = __builtin_amdgcn_mfma_f32_16x16x32_bf16(a, b2f, acc2, 0, 0, 0);
      acc3 = __builtin_amdgcn_mfma_f32_16x16x32_bf16(a, b3f, acc3, 0, 0, 0);
    }
  } else {  // hidden is f32 fallback: load f32, convert to bf16 fragments
    const float* Ap = (const float*)hid + abase;
#pragma unroll 2
    for (int ks = 0; ks < 512; ks += 32) {
      float4 lo = *(const float4*)(Ap + ks);
      float4 hi = *(const float4*)(Ap + ks + 4);
      bf16x8 a;
      a[0] = f2bf(lo.x); a[1] = f2bf(lo.y); a[2] = f2bf(lo.z); a[3] = f2bf(lo.w);
      a[4] = f2bf(hi.x); a[5] = f2bf(hi.y); a[6] = f2bf(hi.z); a[7] = f2bf(hi.w);
      bf16x8 b0  = *(const bf16x8*)(Bp + ks);
      bf16x8 b1f = *(const bf16x8*)(Bp + 16 * D_MODEL + ks);
      bf16x8 b2f = *(const bf16x8*)(Bp + 32 * D_MODEL + ks);
      bf16x8 b3f = *(const bf16x8*)(Bp + 48 * D_MODEL + ks);
      acc0 = __builtin_amdgcn_mfma_f32_16x16x32_bf16(a, b0, acc0, 0, 0, 0);
      acc1 = __builtin_amdgcn_mfma_f32_16x16x32_bf16(a, b1f, acc1, 0, 0, 0);
      acc2 = __builtin_amdgcn_mfma_f32_16x16x32_bf16(a, b2f, acc2, 0, 0, 0);
      acc3 = __builtin_amdgcn_mfma_f32_16x16x32_bf16(a, b3f, acc3, 0, 0, 0);
    }
  }
  __shared__ float red[8][16][64];  // 32 KB
#pragma unroll
  for (int r = 0; r < 4; ++r) {
    int row = kg * 4 + r;
    red[w][row][ 0 + m] = acc0[r];
    red[w][row][16 + m] = acc1[r];
    red[w][row][32 + m] = acc2[r];
    red[w][row][48 + m] = acc3[r];
  }
  __syncthreads();
  // epilogue: thread t -> row = t>>5 (0..15), cid = t&31 handles cols cid, cid+32
  int row = threadIdx.x >> 5, cid = threadIdx.x & 31;
  int fb1 = flags[4], fw2 = flags[3];
  float y = 0.f;
#pragma unroll
  for (int j = 0; j < 2; ++j) {
    int c = cid + 32 * j;
    float s = 0.f;
#pragma unroll
    for (int ch = 0; ch < 8; ++ch) s += red[ch][row][c];
    s += fb1 ? bf2f(b1, c) : ((const float*)b1)[c];
    float g = 0.5f * s * (1.0f + erff(s * 0.70710678118654752f));  // exact GELU
    y += g * (fw2 ? bf2f(w2, c) : ((const float*)w2)[c]);
  }
#pragma unroll
  for (int off = 1; off <= 16; off <<= 1) y += __shfl_xor(y, off, 64);
  if (cid == 0) {
    float x = y + scal[1];  // + b2
    float d = (x > 20.0f) ? x : log1pf(expf(x));  // softplus
    delta[tile * 16 + row] = d;
  }
}

// ---------------------------------------------------------------------------
// Kernel 3: causal EMA, gate, field, mean. OUTPUT IS FLOAT32 (mixed tuple
// (bf16,bf16,f32) concatenated by harness -> numpy-promoted f32).
// ---------------------------------------------------------------------------
__global__ __launch_bounds__(256) void ema_out(const float* __restrict__ delta,
                                               const float* __restrict__ scal,
                                               float* __restrict__ out) {
  int b    = threadIdx.x >> 6;   // batch 0..3
  int lane = threadIdx.x & 63;
  const float alpha = 0.9f;
  float d[32];
  const float* dp = delta + b * SEQ + lane * 32;
  float beta = 0.f, lsum = 0.f;
#pragma unroll
  for (int i = 0; i < 32; ++i) {
    d[i] = dp[i];
    lsum += d[i];
    beta = alpha * beta + 0.1f * d[i];
  }
  float accA = 0.03433683820292512f;  // 0.9^32
  float accB = beta;
  for (int off = 1; off < 64; off <<= 1) {
    float uA = __shfl_up(accA, off, 64);
    float uB = __shfl_up(accB, off, 64);
    if (lane >= off) {
      accB = accB + accA * uB;  // cur o prev
      accA = accA * uA;
    }
  }
  float prev = __shfl_up(accB, 1, 64);
  float h = (lane == 0) ? 0.f : prev;  // carry-in state for this chunk
  float lam = scal[0];
#pragma unroll
  for (int i = 0; i < 32; ++i) {
    h = alpha * h + 0.1f * d[i];
    float gate = 1.0f / (1.0f + expf(lam * h));  // sigmoid(-lam*h)
    out[b * SEQ + lane * 32 + i]        = gate;
    out[NTOK + b * SEQ + lane * 32 + i] = h;
  }
#pragma unroll
  for (int off = 32; off >= 1; off >>= 1) lsum += __shfl_xor(lsum, off, 64);
  __shared__ float bs[4];
  if (lane == 0) bs[b] = lsum;
  __syncthreads();
  if (threadIdx.x == 0)
    out[2 * NTOK] = (bs[0] + bs[1] + bs[2] + bs[3]) * (1.0f / 8192.0f);
}

// ---------------------------------------------------------------------------
extern "C" void kernel_launch(void* const* d_in, const int* in_sizes, int n_in,
                              void* d_out, int out_size, void* d_ws, size_t ws_size,
                              hipStream_t stream) {
  const void* hidden = d_in[0];  // [4,2048,4096]
  const void* Wf     = d_in[1];  // [16,4096]
  const void* W1     = d_in[2];  // [64,4112]
  const void* b1     = d_in[3];  // [64]
  const void* W2     = d_in[4];  // [1,64]
  const void* b2     = d_in[5];  // [1]
  const void* lam    = d_in[6];  // [1]
  float* out = (float*)d_out;    // 16385 f32 (gate 8192 | field 8192 | mean 1)

  char* ws = (char*)d_ws;
  int*   flags = (int*)ws;
  float* scal  = (float*)(ws + 32);
  __hip_bfloat16* W1eff = (__hip_bfloat16*)(ws + 64);
  float* delta = (float*)(ws + 64 + (size_t)64 * D_MODEL * 2);

  sniff_k<<<1, 320, 0, stream>>>(hidden, Wf, W1, W2, b1, b2, lam, flags, scal);
  fold_w1<<<64, 256, 0, stream>>>(W1, Wf, flags, W1eff);
  gemm_delta<<<512, 512, 0, stream>>>(hidden, (const short*)W1eff, b1, W2, flags, scal, delta);
  ema_out<<<1, 256, 0, stream>>>(delta, scal, out);
}

// Round 5
// 238.623 us; speedup vs baseline: 1.0520x; 1.0363x over previous
//
#include <hip/hip_runtime.h>
#include <hip/hip_bf16.h>

#define D_MODEL 4096
#define NTOK    8192   // B*S = 4*2048
#define SEQ     2048

typedef short bf16x8 __attribute__((ext_vector_type(8)));  // 8 bf16 in 4 VGPRs
typedef float f32x4  __attribute__((ext_vector_type(4)));

__device__ inline short f2bf(float x) {
  __hip_bfloat16 h = __float2bfloat16(x);
  return *reinterpret_cast<short*>(&h);
}
__device__ inline float bf2f(const void* p, size_t i) {
  return __bfloat162float(((const __hip_bfloat16*)p)[i]);
}

// ---------------------------------------------------------------------------
// Kernel 0: dtype sniffing (confirmed R3/R4: hidden=bf16, weights=f32; kept
// for robustness). flag=1 -> read as bf16[], flag=0 -> read as float[].
// ---------------------------------------------------------------------------
__global__ __launch_bounds__(320) void sniff_k(const void* hid, const void* wf,
                                               const void* w1, const void* w2,
                                               const void* b1, const void* b2,
                                               const void* lam,
                                               int* flags, float* scal) {
  int wv = threadIdx.x >> 6, lane = threadIdx.x & 63;
  const unsigned short* p = nullptr;
  int n = 0;
  switch (wv) {
    case 0: p = (const unsigned short*)hid; n = NTOK * D_MODEL; break;
    case 1: p = (const unsigned short*)wf;  n = 16 * D_MODEL;   break;
    case 2: p = (const unsigned short*)w1;  n = 64 * 4112;      break;
    case 3: p = (const unsigned short*)w2;  n = 64;             break;
    case 4: p = (const unsigned short*)b1;  n = 64;             break;
  }
  int S = n / 2 < 64 ? n / 2 : 64;
  bool act = lane < S;
  unsigned short ve = 0, vo = 0;
  if (act) { ve = p[2 * lane]; vo = p[2 * lane + 1]; }
  int ee = (ve >> 7) & 0xFF, eo = (vo >> 7) & 0xFF;
  bool ve_band   = (ve == 0) || (ve == 0x8000) || (ee >= 96 && ee <= 141);
  bool vo_bandnz = (vo != 0) && (vo != 0x8000) && (eo >= 96 && eo <= 141);
  int zp = __popcll(__ballot(act && ve == 0 && vo == 0));
  int ob = __popcll(__ballot(act && ve == 0 && vo_bandnz));
  int eb = __popcll(__ballot(act && ve_band));
  if (lane == 0) {
    int f;
    if (zp == S) f = 1;
    else if (4 * ob >= 3 * S) f = 0;    // f32 storage of bf16-rounded values
    else if (4 * eb >= 3 * S) f = 1;    // true bf16
    else f = 0;                         // raw f32
    flags[wv] = f;
  }
  if (threadIdx.x == 0) {
    unsigned short l0 = *(const unsigned short*)lam;
    int le = (l0 >> 7) & 0xFF;
    if (l0 != 0 && l0 != 0x8000 && le >= 96 && le <= 141)
      scal[0] = __bfloat162float(*(const __hip_bfloat16*)lam);
    else
      scal[0] = *(const float*)lam;
    unsigned short c0 = *(const unsigned short*)b2;
    int ce = (c0 >> 7) & 0xFF;
    if (c0 == 0) scal[1] = 0.0f;
    else if (c0 != 0x8000 && ce >= 96 && ce <= 141)
      scal[1] = __bfloat162float(*(const __hip_bfloat16*)b2);
    else
      scal[1] = *(const float*)b2;
  }
}

// ---------------------------------------------------------------------------
// Kernel 1: fold W_fiber into W1 -> W1_eff[64][4096] bf16 (internal format).
// ---------------------------------------------------------------------------
__global__ __launch_bounds__(256) void fold_w1(const void* __restrict__ W1v,
                                               const void* __restrict__ Wfv,
                                               const int* __restrict__ flags,
                                               __hip_bfloat16* __restrict__ W1eff) {
  int n = blockIdx.x;  // 0..63
  int fw1 = flags[2], fwf = flags[1];
  __shared__ float w1b[16];
  if (threadIdx.x < 16) {
    size_t idx = (size_t)n * 4112 + 4096 + threadIdx.x;
    w1b[threadIdx.x] = fw1 ? bf2f(W1v, idx) : ((const float*)W1v)[idx];
  }
  __syncthreads();
  for (int k = threadIdx.x; k < D_MODEL; k += 256) {
    size_t idx = (size_t)n * 4112 + k;
    float v = fw1 ? bf2f(W1v, idx) : ((const float*)W1v)[idx];
#pragma unroll
    for (int f = 0; f < 16; ++f) {
      size_t wi = (size_t)f * D_MODEL + k;
      float wfv = fwf ? bf2f(Wfv, wi) : ((const float*)Wfv)[wi];
      v += w1b[f] * wfv;
    }
    W1eff[(size_t)n * D_MODEL + k] = __float2bfloat16(v);
  }
}

// ---------------------------------------------------------------------------
// Kernel 2: split-K GEMM partials. Grid 512 = 64 M-tiles x 8 K-chunks,
// blockIdx = c*64 + t  (=> XCD = t%8 for all chunks of tile t -> partials
// stay L2-local for delta_ep's matching swizzle).
// Block = 512 thr (8 waves). ALL waves share K-chunk c (512 wide); wave w
// owns strip rows [t*128 + w*16, +16). B-chunk (64x512 bf16 = 64 KB) staged
// once in LDS, XOR-swizzled: slot16B[kb16][n ^ (kb16&7)] -> 8 lanes per
// bank-quad on both ds_write (staging) and ds_read_b128 (frags) = b128
// optimum. Steady loop: 1 A global load (depth-8 reg prefetch) + 4 ds_read
// + 4 MFMA. B global traffic 268 MB (R4) -> 32 MB; A = 67 MB HBM.
// MFMA 16x16x32 bf16: A[m=lane&15][k=8*(lane>>4)+j]; C: col=lane&15,
// row=(lane>>4)*4+reg (m89/m91-verified).
// ---------------------------------------------------------------------------
__global__ __launch_bounds__(512, 4) void gemm_part(const void* __restrict__ hid,
                                                    const short* __restrict__ B_,
                                                    const int* __restrict__ flags,
                                                    float* __restrict__ part) {
  int c = blockIdx.x >> 6;          // K-chunk 0..7
  int t = blockIdx.x & 63;          // M-tile 0..63 (128 rows each)
  int w    = threadIdx.x >> 6;      // wave 0..7 = strip
  int lane = threadIdx.x & 63;
  int m = lane & 15, kg = lane >> 4;

  __shared__ short Bs[64 * 512];    // 64 KB, swizzled 16B slots

  // ---- stage B chunk: wave-uniform row n, lanes sweep kb16 (coalesced 1KB) ----
#pragma unroll
  for (int i = 0; i < 8; ++i) {
    int n    = (threadIdx.x >> 6) + i * 8;   // 0..63
    int kb16 = threadIdx.x & 63;             // 16B unit within chunk row
    bf16x8 v = *(const bf16x8*)(B_ + (size_t)n * D_MODEL + c * 512 + kb16 * 8);
    *(bf16x8*)(Bs + kb16 * 512 + ((n ^ (kb16 & 7)) * 8)) = v;
  }
  __syncthreads();

  // ---- MFMA main loop ----
  f32x4 acc0 = {0.f, 0.f, 0.f, 0.f};
  f32x4 acc1 = acc0, acc2 = acc0, acc3 = acc0;
  size_t abase = (size_t)(t * 128 + w * 16 + m) * D_MODEL + c * 512 + kg * 8;
  if (flags[0]) {  // hidden bf16 (confirmed path)
    const short* Ap = (const short*)hid + abase;
    bf16x8 areg[8];
#pragma unroll
    for (int i = 0; i < 8; ++i) areg[i] = *(const bf16x8*)(Ap + i * 32);
#pragma unroll
    for (int s = 0; s < 16; ++s) {
      bf16x8 a = areg[s & 7];
      if (s + 8 < 16) areg[s & 7] = *(const bf16x8*)(Ap + (s + 8) * 32);
      int kb16 = s * 4 + kg;
      int swz  = (kb16 & 7);
      const short* bp = Bs + kb16 * 512;
      bf16x8 b0 = *(const bf16x8*)(bp + (((m +  0) ^ swz) * 8));
      bf16x8 b1 = *(const bf16x8*)(bp + (((m + 16) ^ swz) * 8));
      bf16x8 b2 = *(const bf16x8*)(bp + (((m + 32) ^ swz) * 8));
      bf16x8 b3 = *(const bf16x8*)(bp + (((m + 48) ^ swz) * 8));
      acc0 = __builtin_amdgcn_mfma_f32_16x16x32_bf16(a, b0, acc0, 0, 0, 0);
      acc1 = __builtin_amdgcn_mfma_f32_16x16x32_bf16(a, b1, acc1, 0, 0, 0);
      acc2 = __builtin_amdgcn_mfma_f32_16x16x32_bf16(a, b2, acc2, 0, 0, 0);
      acc3 = __builtin_amdgcn_mfma_f32_16x16x32_bf16(a, b3, acc3, 0, 0, 0);
    }
  } else {  // hidden f32 fallback
    const float* Ap = (const float*)hid + abase;
#pragma unroll 4
    for (int s = 0; s < 16; ++s) {
      float4 lo = *(const float4*)(Ap + s * 32);
      float4 hi = *(const float4*)(Ap + s * 32 + 4);
      bf16x8 a;
      a[0] = f2bf(lo.x); a[1] = f2bf(lo.y); a[2] = f2bf(lo.z); a[3] = f2bf(lo.w);
      a[4] = f2bf(hi.x); a[5] = f2bf(hi.y); a[6] = f2bf(hi.z); a[7] = f2bf(hi.w);
      int kb16 = s * 4 + kg;
      int swz  = (kb16 & 7);
      const short* bp = Bs + kb16 * 512;
      bf16x8 b0 = *(const bf16x8*)(bp + (((m +  0) ^ swz) * 8));
      bf16x8 b1 = *(const bf16x8*)(bp + (((m + 16) ^ swz) * 8));
      bf16x8 b2 = *(const bf16x8*)(bp + (((m + 32) ^ swz) * 8));
      bf16x8 b3 = *(const bf16x8*)(bp + (((m + 48) ^ swz) * 8));
      acc0 = __builtin_amdgcn_mfma_f32_16x16x32_bf16(a, b0, acc0, 0, 0, 0);
      acc1 = __builtin_amdgcn_mfma_f32_16x16x32_bf16(a, b1, acc1, 0, 0, 0);
      acc2 = __builtin_amdgcn_mfma_f32_16x16x32_bf16(a, b2, acc2, 0, 0, 0);
      acc3 = __builtin_amdgcn_mfma_f32_16x16x32_bf16(a, b3, acc3, 0, 0, 0);
    }
  }

  // ---- store partials: part[c][token][col] ----
  float* po = part + ((size_t)c * NTOK + (size_t)t * 128 + w * 16) * 64;
#pragma unroll
  for (int r = 0; r < 4; ++r) {
    int row = kg * 4 + r;
    po[row * 64 + (m +  0)] = acc0[r];
    po[row * 64 + (m + 16)] = acc1[r];
    po[row * 64 + (m + 32)] = acc2[r];
    po[row * 64 + (m + 48)] = acc3[r];
  }
}

// ---------------------------------------------------------------------------
// Kernel 3: reduce 8 K-chunk partials + b1, exact GELU, dot W2, softplus.
// Grid 512, blockIdx = sub*64 + t (matches gemm's XCD swizzle: block for
// tile t lands on XCD t%8 where its partials are L2-resident).
// Block 256 thr: 16 tokens; thread = (token row 0..15) x (cid 0..15 -> cols
// cid+16j).
// ---------------------------------------------------------------------------
__global__ __launch_bounds__(256) void delta_ep(const float* __restrict__ part,
                                                const void* __restrict__ b1,
                                                const void* __restrict__ w2,
                                                const int* __restrict__ flags,
                                                const float* __restrict__ scal,
                                                float* __restrict__ delta) {
  int t   = blockIdx.x & 63;
  int sub = blockIdx.x >> 6;                 // 0..7
  int tok = t * 128 + sub * 16 + (threadIdx.x >> 4);
  int cid = threadIdx.x & 15;
  int fb1 = flags[4], fw2 = flags[3];
  float y = 0.f;
#pragma unroll
  for (int j = 0; j < 4; ++j) {
    int col = cid + 16 * j;
    float s = 0.f;
#pragma unroll
    for (int c = 0; c < 8; ++c)
      s += part[((size_t)c * NTOK + tok) * 64 + col];
    s += fb1 ? bf2f(b1, col) : ((const float*)b1)[col];
    float g = 0.5f * s * (1.0f + erff(s * 0.70710678118654752f));  // exact GELU
    y += g * (fw2 ? bf2f(w2, col) : ((const float*)w2)[col]);
  }
#pragma unroll
  for (int off = 1; off <= 8; off <<= 1) y += __shfl_xor(y, off, 64);
  if (cid == 0) {
    float x = y + scal[1];  // + b2
    float d = (x > 20.0f) ? x : log1pf(expf(x));  // softplus
    delta[tok] = d;
  }
}

// ---------------------------------------------------------------------------
// Kernel 4: causal EMA, gate, field, mean. OUTPUT IS FLOAT32 (mixed tuple
// (bf16,bf16,f32) concatenated by harness -> numpy-promoted f32).
// ---------------------------------------------------------------------------
__global__ __launch_bounds__(256) void ema_out(const float* __restrict__ delta,
                                               const float* __restrict__ scal,
                                               float* __restrict__ out) {
  int b    = threadIdx.x >> 6;   // batch 0..3
  int lane = threadIdx.x & 63;
  const float alpha = 0.9f;
  float d[32];
  const float* dp = delta + b * SEQ + lane * 32;
  float beta = 0.f, lsum = 0.f;
#pragma unroll
  for (int i = 0; i < 32; ++i) {
    d[i] = dp[i];
    lsum += d[i];
    beta = alpha * beta + 0.1f * d[i];
  }
  float accA = 0.03433683820292512f;  // 0.9^32
  float accB = beta;
  for (int off = 1; off < 64; off <<= 1) {
    float uA = __shfl_up(accA, off, 64);
    float uB = __shfl_up(accB, off, 64);
    if (lane >= off) {
      accB = accB + accA * uB;  // cur o prev
      accA = accA * uA;
    }
  }
  float prev = __shfl_up(accB, 1, 64);
  float h = (lane == 0) ? 0.f : prev;  // carry-in state for this chunk
  float lam = scal[0];
#pragma unroll
  for (int i = 0; i < 32; ++i) {
    h = alpha * h + 0.1f * d[i];
    float gate = 1.0f / (1.0f + expf(lam * h));  // sigmoid(-lam*h)
    out[b * SEQ + lane * 32 + i]        = gate;
    out[NTOK + b * SEQ + lane * 32 + i] = h;
  }
#pragma unroll
  for (int off = 32; off >= 1; off >>= 1) lsum += __shfl_xor(lsum, off, 64);
  __shared__ float bs[4];
  if (lane == 0) bs[b] = lsum;
  __syncthreads();
  if (threadIdx.x == 0)
    out[2 * NTOK] = (bs[0] + bs[1] + bs[2] + bs[3]) * (1.0f / 8192.0f);
}

// ---------------------------------------------------------------------------
extern "C" void kernel_launch(void* const* d_in, const int* in_sizes, int n_in,
                              void* d_out, int out_size, void* d_ws, size_t ws_size,
                              hipStream_t stream) {
  const void* hidden = d_in[0];  // [4,2048,4096]
  const void* Wf     = d_in[1];  // [16,4096]
  const void* W1     = d_in[2];  // [64,4112]
  const void* b1     = d_in[3];  // [64]
  const void* W2     = d_in[4];  // [1,64]
  const void* b2     = d_in[5];  // [1]
  const void* lam    = d_in[6];  // [1]
  float* out = (float*)d_out;    // 16385 f32 (gate 8192 | field 8192 | mean 1)

  // ws: [0,32) flags, [32,64) scal, [64, +512K) W1eff bf16, [+32K) delta f32,
  // then part f32 [8][8192][64] = 16 MB.
  char* ws = (char*)d_ws;
  int*   flags = (int*)ws;
  float* scal  = (float*)(ws + 32);
  __hip_bfloat16* W1eff = (__hip_bfloat16*)(ws + 64);
  float* delta = (float*)(ws + 64 + (size_t)64 * D_MODEL * 2);
  float* part  = (float*)(ws + 64 + (size_t)64 * D_MODEL * 2 + NTOK * 4);

  sniff_k<<<1, 320, 0, stream>>>(hidden, Wf, W1, W2, b1, b2, lam, flags, scal);
  fold_w1<<<64, 256, 0, stream>>>(W1, Wf, flags, W1eff);
  gemm_part<<<512, 512, 0, stream>>>(hidden, (const short*)W1eff, flags, part);
  delta_ep<<<512, 256, 0, stream>>>(part, b1, W2, flags, scal, delta);
  ema_out<<<1, 256, 0, stream>>>(delta, scal, out);
}